// Round 16
// baseline (700.916 us; speedup 1.0000x reference)
//
#include <hip/hip_runtime.h>
#include <hip/hip_bf16.h>
#include <hip/hip_cooperative_groups.h>

namespace cg = cooperative_groups;

// GCN: h1 = relu(Dinv (A+I) Dinv (x W1) + b1); h2 = relu(same with W2);
// out = mean-pool-by-graph(h2) @ Wl + bl.
// Identity: hs[u] = (xW)[u]*dinv[u]; conv[v] = dinv[v]*(hs[v] + sum_in hs[u]) + b.
// R16: 4 sort kernels fused into ONE cooperative kernel — but unlike R14
// (421us: ESLOT reg arrays spilled at 1024thr -> VALU 1.2%), edges are
// RE-READ from global in the scatter phase (12.8MB, L3-warm, ~2us) instead
// of held in registers. Phases: A hist(+prep blk0) / B column-scan / C
// scatter / D bfill, separated by grid.sync. Kills 3 launch gaps + keeps
// ebuf L2-warm into phase D. Convs/gemms unchanged from R12 (68us conv).

#define HDIM 64
#define NB 256      // dst-range buckets == grid blocks (N <= 131072)

typedef __attribute__((ext_vector_type(8))) short short8;   // 8 bf16 (4 VGPRs)
typedef __attribute__((ext_vector_type(4))) float f32x4;
typedef __attribute__((ext_vector_type(2))) float f32x2;
union FragU { uint4 u; short8 s; };

static __device__ __forceinline__ unsigned bf16_bits(float f) {  // RNE
    unsigned u = __float_as_uint(f);
    return (u + 0x7fff + ((u >> 16) & 1)) >> 16;
}
static __device__ __forceinline__ float bflo(unsigned w) { return __uint_as_float(w << 16); }
static __device__ __forceinline__ float bfhi(unsigned w) { return __uint_as_float(w & 0xffff0000u); }

// ---------------- cooperative CSR build (re-read variant) ----------------
__global__ __launch_bounds__(1024) void k_sort2(const int* __restrict__ src,
        const int* __restrict__ dst, int* __restrict__ blkhist, int* __restrict__ bcnt,
        unsigned* __restrict__ ebuf, int4* __restrict__ meta, float* __restrict__ dinv,
        int* __restrict__ csr, const float* __restrict__ W1, const float* __restrict__ W2,
        uint4* __restrict__ W1s, uint4* __restrict__ W2s, unsigned* __restrict__ hsbA,
        unsigned* __restrict__ hsbB, int N, int E, int npb, int chunk) {
    cg::grid_group grid = cg::this_grid();
    __shared__ int smem[1542];                // reused across phases (~6.2KB)
    int b = blockIdx.x, tid = threadIdx.x;
    int e0 = b * chunk, e1 = min(E, e0 + chunk);
    int g0 = e0 >> 2, ng = (e1 - e0) >> 2;    // chunk %4==0 by construction
    const int4* dst4 = (const int4*)dst;
    const int4* src4 = (const int4*)src;

    // ---- Phase A: 4x-replicated LDS histogram of dst buckets ----
    {
        int* lh = smem;                       // [4*257]
        for (int i = tid; i < 4 * 257; i += 1024) lh[i] = 0;
        __syncthreads();
        int cp = (tid & 3) * 257;
        for (int g = g0 + tid; g < g0 + ng; g += 1024) {
            int4 d4 = dst4[g];
            atomicAdd(&lh[cp + (unsigned)d4.x / (unsigned)npb], 1);
            atomicAdd(&lh[cp + (unsigned)d4.y / (unsigned)npb], 1);
            atomicAdd(&lh[cp + (unsigned)d4.z / (unsigned)npb], 1);
            atomicAdd(&lh[cp + (unsigned)d4.w / (unsigned)npb], 1);
        }
        for (int e = e0 + ng * 4 + tid; e < e1; e += 1024)   // tail
            atomicAdd(&lh[cp + (unsigned)dst[e] / (unsigned)npb], 1);
        __syncthreads();
        if (tid < NB)
            blkhist[b * NB + tid] = lh[tid] + lh[257 + tid] + lh[514 + tid] + lh[771 + tid];
    }
    if (b == 0) {   // overlapped prep: W swizzle + zero pad-rows
        int lane = tid & 63, ci = tid >> 6;
        {   // W1: K=128 -> 4 ktiles x 4 ntiles
            int kt = ci >> 2, nt = ci & 3;
            int kbase = kt * 32 + (lane >> 4) * 8;
            int n = nt * 16 + (lane & 15);
            uint4 o; unsigned* op = (unsigned*)&o;
            for (int jj = 0; jj < 4; ++jj) {
                unsigned lo = bf16_bits(W1[(kbase + 2 * jj) * 64 + n]);
                unsigned hi = bf16_bits(W1[(kbase + 2 * jj + 1) * 64 + n]);
                op[jj] = lo | (hi << 16);
            }
            W1s[ci * 64 + lane] = o;
        }
        if (ci < 8) {  // W2: K=64 -> 2 ktiles x 4 ntiles
            int kt = ci >> 2, nt = ci & 3;
            int kbase = kt * 32 + (lane >> 4) * 8;
            int n = nt * 16 + (lane & 15);
            uint4 o; unsigned* op = (unsigned*)&o;
            for (int jj = 0; jj < 4; ++jj) {
                unsigned lo = bf16_bits(W2[(kbase + 2 * jj) * 64 + n]);
                unsigned hi = bf16_bits(W2[(kbase + 2 * jj + 1) * 64 + n]);
                op[jj] = lo | (hi << 16);
            }
            W2s[ci * 64 + lane] = o;
        }
        // zero row N (padding target). hsbA aliases ebuf but row N begins at
        // byte E*4 == end of ebuf's used range: disjoint from phase-C scatter.
        if (tid < 32) hsbA[(size_t)N * 32 + tid] = 0;
        else if (tid < 64) hsbB[(size_t)N * 32 + (tid - 32)] = 0;
    }
    __threadfence();
    grid.sync();

    // ---- Phase B: block b scans column blkhist[*][b] (exclusive, in place) ----
    {
        int* s = smem;                        // [256]
        int orig = 0;
        if (tid < NB) { orig = blkhist[tid * NB + b]; s[tid] = orig; }
        __syncthreads();
        for (int off = 1; off < NB; off <<= 1) {
            int v = 0;
            if (tid < NB && tid >= off) v = s[tid - off];
            __syncthreads();
            if (tid < NB) s[tid] += v;
            __syncthreads();
        }
        if (tid < NB) blkhist[tid * NB + b] = s[tid] - orig;
        if (tid == NB - 1) bcnt[b] = s[tid];
    }
    __threadfence();
    grid.sync();

    // ---- Phase C: local bstart scan; re-read edges; scatter ----
    int ed0, ed1;                             // this bucket's ebuf range (for D)
    {
        int* sc   = smem;                     // [256] inclusive scan of bcnt
        int* base = smem + 256;               // [256]
        int* lcur = smem + 512;               // [256]
        int orig = 0;
        if (tid < NB) { orig = bcnt[tid]; sc[tid] = orig; }
        __syncthreads();
        for (int off = 1; off < NB; off <<= 1) {
            int v = 0;
            if (tid < NB && tid >= off) v = sc[tid - off];
            __syncthreads();
            if (tid < NB) sc[tid] += v;
            __syncthreads();
        }
        if (tid < NB) {
            base[tid] = (sc[tid] - orig) + blkhist[b * NB + tid];
            lcur[tid] = 0;
        }
        __syncthreads();
        ed1 = sc[b];
        ed0 = ed1 - bcnt[b];
        __syncthreads();
        for (int g = g0 + tid; g < g0 + ng; g += 1024) {
            int4 d4 = dst4[g];
            int4 s4 = src4[g];
            #define SCAT(D, S) {                                               \
                unsigned bb = (unsigned)(D) / (unsigned)npb;                   \
                unsigned ld = (unsigned)(D) - bb * (unsigned)npb;              \
                int off = atomicAdd(&lcur[bb], 1);                             \
                ebuf[base[bb] + off] = (ld << 17) | (unsigned)(S); }
            SCAT(d4.x, s4.x) SCAT(d4.y, s4.y) SCAT(d4.z, s4.z) SCAT(d4.w, s4.w)
        }
        for (int e = e0 + ng * 4 + tid; e < e1; e += 1024) {  // tail
            SCAT(dst[e], src[e])
        }
        #undef SCAT
    }
    __threadfence();
    grid.sync();

    // ---- Phase D: per-bucket node histogram -> padded scan -> meta/csr ----
    {
        int* h = smem;                        // [512]
        int* p = smem + 512;                  // [512]
        int* c = smem + 1024;                 // [512]
        int vlo = b * npb;
        int vcnt = min(npb, N - vlo);
        if (vcnt <= 0) return;                // uniform across block
        for (int i = tid; i < 512; i += 1024) h[i] = 0;
        __syncthreads();
        for (int e = ed0 + tid; e < ed1; e += 1024)
            atomicAdd(&h[ebuf[e] >> 17], 1);
        __syncthreads();
        int pc = 0;
        if (tid < 512) {
            pc = (tid < vcnt) ? ((h[tid] + 7) & ~7) : 0;   // padded count
            p[tid] = pc;
        }
        __syncthreads();
        for (int off = 1; off < 512; off <<= 1) {
            int v = 0;
            if (tid < 512 && tid >= off) v = p[tid - off];
            __syncthreads();
            if (tid < 512) p[tid] += v;
            __syncthreads();
        }
        int bb = ed0 + 7 * vlo;               // padded bucket base (csr sized E+7N)
        if (tid < vcnt) {
            int excl = p[tid] - pc;
            int v = vlo + tid;
            float di = rsqrtf((float)(h[tid] + 1));
            meta[v] = make_int4(bb + excl, pc >> 3, __float_as_int(di), 0);
            dinv[v] = di;
            c[tid] = excl;
        }
        __syncthreads();
        for (int e = ed0 + tid; e < ed1; e += 1024) {
            unsigned ed = ebuf[e];
            int off = atomicAdd(&c[ed >> 17], 1);
            csr[bb + off] = (int)(ed & 0x1FFFFu);
        }
        __syncthreads();
        if (tid < vcnt) {                     // zero-row padding entries
            int excl = p[tid] - pc;
            for (int q = excl + h[tid]; q < excl + pc; ++q) csr[bb + q] = N;
        }
    }
}

// ---------------- MFMA GEMMs ----------------
// D col=lane&15 (feature in ntile), row=(lane>>4)*4+r (node in 16).
#define MFMA_EPILOGUE(OUT)                                                     \
    {                                                                          \
        int col = lane & 15;                                                   \
        float dv[4];                                                           \
        for (int r = 0; r < 4; ++r) {                                          \
            int vr = v0 + quad * 4 + r;                                        \
            dv[r] = dinv[vr < n ? vr : (n - 1)];                               \
        }                                                                      \
        for (int nt = 0; nt < 4; ++nt)                                         \
            for (int r = 0; r < 4; ++r) {                                      \
                int vr = v0 + quad * 4 + r;                                    \
                float val = acc[nt][r] * dv[r];                                \
                float oth = __shfl_xor(val, 1, 64);                            \
                if (!(lane & 1) && vr < n)                                     \
                    OUT[(size_t)vr * 32 + nt * 8 + (col >> 1)] =               \
                        bf16_bits(val) | (bf16_bits(oth) << 16);               \
            }                                                                  \
    }

// hs1 = dinv * (X @ W1). X staged via wave-private LDS (coalesced 1KB loads).
__global__ __launch_bounds__(256) void k_mgemm1(const float* __restrict__ X,
        const uint4* __restrict__ W1s, const float* __restrict__ dinv,
        unsigned* __restrict__ hsb, int n) {
    __shared__ float Xs[4][16 * 132];         // 16 rows, +4 pad per row
    int lane = threadIdx.x & 63, wv = threadIdx.x >> 6;
    int v0 = (blockIdx.x * 4 + wv) * 16;
    if (v0 >= n) return;                      // wave-uniform
    const float4* X4 = (const float4*)X;
#pragma unroll
    for (int i = 0; i < 8; ++i) {             // stage 16 rows (8KB), coalesced
        int gi = i * 64 + lane;
        int r = gi >> 5, c4 = gi & 31;
        int vr = v0 + r; if (vr >= n) vr = n - 1;
        float4 t = X4[(size_t)vr * 32 + c4];
        *(float4*)&Xs[wv][r * 132 + c4 * 4] = t;
    }
    // wave-private LDS: no barrier needed
    int quad = lane >> 4;
    const float* xr = &Xs[wv][(lane & 15) * 132 + quad * 8];
    f32x4 acc[4] = {f32x4{0,0,0,0}, f32x4{0,0,0,0}, f32x4{0,0,0,0}, f32x4{0,0,0,0}};
#pragma unroll
    for (int kt = 0; kt < 4; ++kt) {
        float4 xa = *(const float4*)(xr + kt * 32);
        float4 xb = *(const float4*)(xr + kt * 32 + 4);
        FragU a;
        a.u.x = bf16_bits(xa.x) | (bf16_bits(xa.y) << 16);
        a.u.y = bf16_bits(xa.z) | (bf16_bits(xa.w) << 16);
        a.u.z = bf16_bits(xb.x) | (bf16_bits(xb.y) << 16);
        a.u.w = bf16_bits(xb.z) | (bf16_bits(xb.w) << 16);
#pragma unroll
        for (int nt = 0; nt < 4; ++nt) {
            FragU bfr; bfr.u = W1s[(kt * 4 + nt) * 64 + lane];
            acc[nt] = __builtin_amdgcn_mfma_f32_16x16x32_bf16(a.s, bfr.s, acc[nt], 0, 0, 0);
        }
    }
    MFMA_EPILOGUE(hsb)
}

// hs2 = dinv * (h1 @ W2), h1 bf16-packed [N,32 uints], out same format
__global__ __launch_bounds__(256) void k_mgemm2(const unsigned* __restrict__ h1b,
        const uint4* __restrict__ W2s, const float* __restrict__ dinv,
        unsigned* __restrict__ hsbB, int n) {
    int lane = threadIdx.x & 63, wv = threadIdx.x >> 6;
    int v0 = (blockIdx.x * 4 + wv) * 16;
    if (v0 >= n) return;
    int quad = lane >> 4;
    int vm = v0 + (lane & 15); if (vm >= n) vm = n - 1;
    const uint4* h4 = (const uint4*)h1b;
    f32x4 acc[4] = {f32x4{0,0,0,0}, f32x4{0,0,0,0}, f32x4{0,0,0,0}, f32x4{0,0,0,0}};
#pragma unroll
    for (int kt = 0; kt < 2; ++kt) {
        FragU a; a.u = h4[(size_t)vm * 8 + kt * 4 + quad];
#pragma unroll
        for (int nt = 0; nt < 4; ++nt) {
            FragU bfr; bfr.u = W2s[(kt * 4 + nt) * 64 + lane];
            acc[nt] = __builtin_amdgcn_mfma_f32_16x16x32_bf16(a.s, bfr.s, acc[nt], 0, 0, 0);
        }
    }
    MFMA_EPILOGUE(hsbB)
}

// ---------------- conv gather (wave per node, padded, shfl broadcast) -------
#define GATHER_BODY                                                            \
    const uint4* hs4p = (const uint4*)hsb;                                     \
    int o = lane & 7, oct = lane >> 3;                                         \
    int4 mt = meta[v];                                                         \
    int rs = mt.x, nb = mt.y;                                                  \
    float dv = __int_as_float(mt.z);                                           \
    f32x2 A0 = {0.f,0.f}, A1 = {0.f,0.f}, A2 = {0.f,0.f}, A3 = {0.f,0.f};      \
    if (oct == 0) {                                                            \
        uint4 s = hs4p[(size_t)v * 8 + o];                                     \
        A0 = (f32x2){bflo(s.x), bfhi(s.x)};                                    \
        A1 = (f32x2){bflo(s.y), bfhi(s.y)};                                    \
        A2 = (f32x2){bflo(s.z), bfhi(s.z)};                                    \
        A3 = (f32x2){bflo(s.w), bfhi(s.w)};                                    \
    }                                                                          \
    for (int base = 0; base < nb; base += 8) {                                 \
        int idx = csr[rs + base * 8 + lane];  /* overread ok: csr has slack */ \
        int m = nb - base; if (m > 8) m = 8;  /* wave-uniform */               \
        uint4 wb[8];                                                           \
        _Pragma("unroll")                                                      \
        for (int i = 0; i < 8; ++i)                                            \
            if (i < m) {                                                       \
                int u = __shfl(idx, i * 8 + oct, 64);                          \
                wb[i] = hs4p[(size_t)u * 8 + o];                               \
            }                                                                  \
        _Pragma("unroll")                                                      \
        for (int i = 0; i < 8; ++i)                                            \
            if (i < m) {                                                       \
                A0 += (f32x2){bflo(wb[i].x), bfhi(wb[i].x)};                   \
                A1 += (f32x2){bflo(wb[i].y), bfhi(wb[i].y)};                   \
                A2 += (f32x2){bflo(wb[i].z), bfhi(wb[i].z)};                   \
                A3 += (f32x2){bflo(wb[i].w), bfhi(wb[i].w)};                   \
            }                                                                  \
    }                                                                          \
    A0.x += __shfl_xor(A0.x, 8, 64); A0.x += __shfl_xor(A0.x, 16, 64);         \
    A0.x += __shfl_xor(A0.x, 32, 64);                                          \
    A0.y += __shfl_xor(A0.y, 8, 64); A0.y += __shfl_xor(A0.y, 16, 64);         \
    A0.y += __shfl_xor(A0.y, 32, 64);                                          \
    A1.x += __shfl_xor(A1.x, 8, 64); A1.x += __shfl_xor(A1.x, 16, 64);         \
    A1.x += __shfl_xor(A1.x, 32, 64);                                          \
    A1.y += __shfl_xor(A1.y, 8, 64); A1.y += __shfl_xor(A1.y, 16, 64);         \
    A1.y += __shfl_xor(A1.y, 32, 64);                                          \
    A2.x += __shfl_xor(A2.x, 8, 64); A2.x += __shfl_xor(A2.x, 16, 64);         \
    A2.x += __shfl_xor(A2.x, 32, 64);                                          \
    A2.y += __shfl_xor(A2.y, 8, 64); A2.y += __shfl_xor(A2.y, 16, 64);         \
    A2.y += __shfl_xor(A2.y, 32, 64);                                          \
    A3.x += __shfl_xor(A3.x, 8, 64); A3.x += __shfl_xor(A3.x, 16, 64);         \
    A3.x += __shfl_xor(A3.x, 32, 64);                                          \
    A3.y += __shfl_xor(A3.y, 8, 64); A3.y += __shfl_xor(A3.y, 16, 64);         \
    A3.y += __shfl_xor(A3.y, 32, 64);                                          \
    float4 bb0 = ((const float4*)bias)[2 * o];                                 \
    float4 bb1 = ((const float4*)bias)[2 * o + 1];                             \
    float r0 = fmaxf(fmaf(dv, A0.x, bb0.x), 0.f);                              \
    float r1 = fmaxf(fmaf(dv, A0.y, bb0.y), 0.f);                              \
    float r2 = fmaxf(fmaf(dv, A1.x, bb0.z), 0.f);                              \
    float r3 = fmaxf(fmaf(dv, A1.y, bb0.w), 0.f);                              \
    float r4 = fmaxf(fmaf(dv, A2.x, bb1.x), 0.f);                              \
    float r5 = fmaxf(fmaf(dv, A2.y, bb1.y), 0.f);                              \
    float r6 = fmaxf(fmaf(dv, A3.x, bb1.z), 0.f);                              \
    float r7 = fmaxf(fmaf(dv, A3.y, bb1.w), 0.f);

// conv1: gather hs1, h1 = relu(dinv*acc + b1), store h1 bf16-packed.
__global__ void k_conv1(const unsigned* __restrict__ hsb, const int4* __restrict__ meta,
                        const int* __restrict__ csr, const float* __restrict__ bias,
                        unsigned* __restrict__ h1b, int n) {
    int v = (blockIdx.x * 256 + threadIdx.x) >> 6;
    int lane = threadIdx.x & 63;
    if (v >= n) return;
    GATHER_BODY
    if (oct == 0) {
        uint4 pk;
        pk.x = bf16_bits(r0) | (bf16_bits(r1) << 16);
        pk.y = bf16_bits(r2) | (bf16_bits(r3) << 16);
        pk.z = bf16_bits(r4) | (bf16_bits(r5) << 16);
        pk.w = bf16_bits(r6) | (bf16_bits(r7) << 16);
        ((uint4*)h1b)[(size_t)v * 8 + o] = pk;
    }
}

// conv2 + head: gather hs2, h2 = relu(dinv*acc + b2), z[v] = h2 @ Wl.
__global__ void k_conv_out(const unsigned* __restrict__ hsb, const int4* __restrict__ meta,
                           const int* __restrict__ csr, const float* __restrict__ bias,
                           const float* __restrict__ Wl, float2* __restrict__ z, int n) {
    int v = (blockIdx.x * 256 + threadIdx.x) >> 6;
    int lane = threadIdx.x & 63;
    if (v >= n) return;
    GATHER_BODY
    const float4* Wl4 = (const float4*)Wl;    // [64][2] -> 2 rows per float4
    float4 wA = Wl4[4 * o + 0];
    float4 wB = Wl4[4 * o + 1];
    float4 wC = Wl4[4 * o + 2];
    float4 wD = Wl4[4 * o + 3];
    float c0 = r0*wA.x + r1*wA.z + r2*wB.x + r3*wB.z + r4*wC.x + r5*wC.z + r6*wD.x + r7*wD.z;
    float c1 = r0*wA.y + r1*wA.w + r2*wB.y + r3*wB.w + r4*wC.y + r5*wC.w + r6*wD.y + r7*wD.w;
    c0 += __shfl_xor(c0, 1, 64); c1 += __shfl_xor(c1, 1, 64);
    c0 += __shfl_xor(c0, 2, 64); c1 += __shfl_xor(c1, 2, 64);
    c0 += __shfl_xor(c0, 4, 64); c1 += __shfl_xor(c1, 4, 64);
    if (lane == 0) z[v] = make_float2(c0, c1);
}

static __device__ __forceinline__ int lower_bound(const int* __restrict__ a, int n, int key) {
    int lo = 0, hi = n;
    while (lo < hi) {
        int mid = (lo + hi) >> 1;
        if (a[mid] < key) lo = mid + 1; else hi = mid;
    }
    return lo;
}

// One wave per graph: out[g] = mean(z[lo:hi]) + bl  (batch sorted).
__global__ void k_pool_z(const float2* __restrict__ z, const int* __restrict__ batch,
                         const float* __restrict__ bl, float* __restrict__ out, int N, int B) {
    int g = (blockIdx.x * 256 + threadIdx.x) >> 6;
    int lane = threadIdx.x & 63;
    if (g >= B) return;
    int lo = lower_bound(batch, N, g);
    int hi = lower_bound(batch, N, g + 1);
    float c0 = 0.f, c1 = 0.f;
    for (int v = lo + lane; v < hi; v += 64) {
        float2 t = z[v];
        c0 += t.x; c1 += t.y;
    }
    #pragma unroll
    for (int off = 32; off; off >>= 1) {
        c0 += __shfl_xor(c0, off, 64);
        c1 += __shfl_xor(c1, off, 64);
    }
    if (lane == 0) {
        float inv = 1.0f / fmaxf((float)(hi - lo), 1.0f);
        out[g * 2 + 0] = c0 * inv + bl[0];
        out[g * 2 + 1] = c1 * inv + bl[1];
    }
}

extern "C" void kernel_launch(void* const* d_in, const int* in_sizes, int n_in,
                              void* d_out, int out_size, void* d_ws, size_t ws_size,
                              hipStream_t stream) {
    const float* x  = (const float*)d_in[0];   // [N,128] f32
    const int* edge = (const int*)d_in[1];     // [2,E] i32
    const int* batch= (const int*)d_in[2];     // [N] i32 (sorted)
    const float* W1 = (const float*)d_in[3];   // [128,64]
    const float* b1 = (const float*)d_in[4];   // [64]
    const float* W2 = (const float*)d_in[5];   // [64,64]
    const float* b2 = (const float*)d_in[6];   // [64]
    const float* Wl = (const float*)d_in[7];   // [64,2]
    const float* bl = (const float*)d_in[8];   // [2]
    float* out = (float*)d_out;

    const int N = in_sizes[2];
    const int E = in_sizes[1] / 2;
    const int B = out_size / 2;
    const int* srcp = edge;
    const int* dstp = edge + E;
    const int npb = (N + NB - 1) / NB;         // nodes per bucket (391 @ N=100K, <=512)

    // workspace carve-up (256B aligned); ~60 MB
    char* w = (char*)d_ws;
    auto carve = [&](size_t bytes) { void* p = (void*)w; w += (bytes + 255) & ~(size_t)255; return p; };
    int4*     meta    = (int4*)carve((size_t)N * 16);
    float*    dinv    = (float*)carve((size_t)N * 4);
    int*      bcnt    = (int*)carve((NB + 8) * 4);
    int*      blkhist = (int*)carve((size_t)NB * NB * 4);
    uint4*    W1s     = (uint4*)carve(16 * 64 * 16);
    uint4*    W2s     = (uint4*)carve(8 * 64 * 16);
    int*      csr     = (int*)carve(((size_t)E + 7 * (size_t)N + 256) * 4);  // padded rows
    // ebuf aliases hsbA: ebuf uses [0, E*4); hsbA rows 0..N-1 use the same
    // range (E==32N), row N sits just past it. ebuf is dead after k_sort2.
    unsigned* hsbA    = (unsigned*)carve(((size_t)N + 1) * 32 * 4);
    unsigned* ebuf    = hsbA;
    unsigned* h1b     = (unsigned*)carve(((size_t)N + 1) * 32 * 4);  // bf16x2 relu'd h1
    unsigned* hsbB    = (unsigned*)carve(((size_t)N + 1) * 32 * 4);  // bf16x2 hs layer2
    float2*   zbuf    = (float2*)carve((size_t)N * 8);               // per-node head output

    int chunk = ((E + NB - 1) / NB + 3) & ~3;  // edges per block, %4==0
    int wbl = (N + 3) / 4;                     // 4 waves (nodes) per 256-thread block
    int gbl = (N + 63) / 64;                   // 64 nodes per MFMA-gemm block

    int Nv = N, Ev = E, npbv = npb, chunkv = chunk;
    void* args[] = {
        (void*)&srcp, (void*)&dstp, (void*)&blkhist, (void*)&bcnt, (void*)&ebuf,
        (void*)&meta, (void*)&dinv, (void*)&csr, (void*)&W1, (void*)&W2,
        (void*)&W1s, (void*)&W2s, (void*)&hsbA, (void*)&hsbB,
        (void*)&Nv, (void*)&Ev, (void*)&npbv, (void*)&chunkv
    };
    hipLaunchCooperativeKernel((void*)k_sort2, dim3(NB), dim3(1024), args, 0, stream);

    k_mgemm1<<<gbl, 256, 0, stream>>>(x, W1s, dinv, hsbA, N);
    k_conv1<<<wbl, 256, 0, stream>>>(hsbA, meta, csr, b1, h1b, N);
    k_mgemm2<<<gbl, 256, 0, stream>>>(h1b, W2s, dinv, hsbB, N);
    k_conv_out<<<wbl, 256, 0, stream>>>(hsbB, meta, csr, b2, Wl, zbuf, N);

    k_pool_z<<<(B * 64 + 255) / 256, 256, 0, stream>>>(zbuf, batch, bl, out, N, B);
}

// Round 17
// 304.984 us; speedup vs baseline: 2.2982x; 2.2982x over previous
//
#include <hip/hip_runtime.h>
#include <hip/hip_bf16.h>

// GCN: h1 = relu(Dinv (A+I) Dinv (x W1) + b1); h2 = relu(same with W2);
// out = mean-pool-by-graph(h2) @ Wl + bl.
// Identity: hs[u] = (xW)[u]*dinv[u]; conv[v] = dinv[v]*(hs[v] + sum_in hs[u]) + b.
// R17: cooperative fusion abandoned — R14 (421us, spilled regs) vs R16 (430us,
// no spill) proves grid.sync() itself costs ~70-100us/sync on 8-XCD MI355X.
// Instead: bcount+bscan2+bscatter replaced by ONE cursor-scatter kernel using
// fixed-capacity bucket regions (CAP~1.7x mean; binomial sigma=112 -> overflow
// impossible, clamped anyway). csr also fixed-cap/bucket; bfill reads bucket
// count straight from the cursor. No global prefix scans at all.
// Convs/gemms/pool unchanged from R12/R15 (proven 68us conv).

#define HDIM 64
#define NB 256      // dst-range buckets (N <= 131072: src fits 17 bits, local dst 9)
#define SGRID 256   // blocks for scatter

typedef __attribute__((ext_vector_type(8))) short short8;   // 8 bf16 (4 VGPRs)
typedef __attribute__((ext_vector_type(4))) float f32x4;
typedef __attribute__((ext_vector_type(2))) float f32x2;
union FragU { uint4 u; short8 s; };

static __device__ __forceinline__ unsigned bf16_bits(float f) {  // RNE
    unsigned u = __float_as_uint(f);
    return (u + 0x7fff + ((u >> 16) & 1)) >> 16;
}
static __device__ __forceinline__ float bflo(unsigned w) { return __uint_as_float(w << 16); }
static __device__ __forceinline__ float bfhi(unsigned w) { return __uint_as_float(w & 0xffff0000u); }

// ---------------- CSR build: cursor scatter + per-bucket fill ----------------

// Blocks 0..SGRID-1: LDS histogram of own chunk -> one global atomicAdd per
// bucket to reserve a run in bucket region [b*cap ...] -> re-read chunk
// (L2-warm, ~100KB) and scatter. Block SGRID: W swizzle prep.
__global__ __launch_bounds__(1024) void k_scatter(const int* __restrict__ src,
        const int* __restrict__ dst, int* __restrict__ bcur, unsigned* __restrict__ ebuf,
        const float* __restrict__ W1, const float* __restrict__ W2,
        uint4* __restrict__ W1s, uint4* __restrict__ W2s,
        int N, int E, int npb, int chunk, int cap) {
    int tid = threadIdx.x;
    if (blockIdx.x == SGRID) {   // prep block: W swizzle only
        int lane = tid & 63, ci = tid >> 6;
        {   // W1: K=128 -> 4 ktiles x 4 ntiles
            int kt = ci >> 2, nt = ci & 3;
            int kbase = kt * 32 + (lane >> 4) * 8;
            int n = nt * 16 + (lane & 15);
            uint4 o; unsigned* op = (unsigned*)&o;
            for (int jj = 0; jj < 4; ++jj) {
                unsigned lo = bf16_bits(W1[(kbase + 2 * jj) * 64 + n]);
                unsigned hi = bf16_bits(W1[(kbase + 2 * jj + 1) * 64 + n]);
                op[jj] = lo | (hi << 16);
            }
            W1s[ci * 64 + lane] = o;
        }
        if (ci < 8) {  // W2: K=64 -> 2 ktiles x 4 ntiles
            int kt = ci >> 2, nt = ci & 3;
            int kbase = kt * 32 + (lane >> 4) * 8;
            int n = nt * 16 + (lane & 15);
            uint4 o; unsigned* op = (unsigned*)&o;
            for (int jj = 0; jj < 4; ++jj) {
                unsigned lo = bf16_bits(W2[(kbase + 2 * jj) * 64 + n]);
                unsigned hi = bf16_bits(W2[(kbase + 2 * jj + 1) * 64 + n]);
                op[jj] = lo | (hi << 16);
            }
            W2s[ci * 64 + lane] = o;
        }
        return;
    }
    __shared__ int lh[4 * 257];
    __shared__ int base[NB], lcur[NB];
    int b = blockIdx.x;
    int e0 = b * chunk, e1 = min(E, e0 + chunk);
    int g0 = e0 >> 2, ng = (e1 - e0) >> 2;    // chunk %4==0 by construction
    const int4* dst4 = (const int4*)dst;
    const int4* src4 = (const int4*)src;
    for (int i = tid; i < 4 * 257; i += 1024) lh[i] = 0;
    __syncthreads();
    int cp = (tid & 3) * 257;
    for (int g = g0 + tid; g < g0 + ng; g += 1024) {
        int4 d4 = dst4[g];
        atomicAdd(&lh[cp + (unsigned)d4.x / (unsigned)npb], 1);
        atomicAdd(&lh[cp + (unsigned)d4.y / (unsigned)npb], 1);
        atomicAdd(&lh[cp + (unsigned)d4.z / (unsigned)npb], 1);
        atomicAdd(&lh[cp + (unsigned)d4.w / (unsigned)npb], 1);
    }
    for (int e = e0 + ng * 4 + tid; e < e1; e += 1024)       // tail
        atomicAdd(&lh[cp + (unsigned)dst[e] / (unsigned)npb], 1);
    __syncthreads();
    if (tid < NB) {
        int tot = lh[tid] + lh[257 + tid] + lh[514 + tid] + lh[771 + tid];
        base[tid] = tid * cap + (tot ? atomicAdd(&bcur[tid], tot) : 0);
        lcur[tid] = 0;
    }
    __syncthreads();
    unsigned ebtot = (unsigned)NB * (unsigned)cap;           // memory-safety clamp
    for (int g = g0 + tid; g < g0 + ng; g += 1024) {         // re-read (L2-warm)
        int4 d4 = dst4[g];
        int4 s4 = src4[g];
        #define SCAT(D, S) {                                                   \
            unsigned bb = (unsigned)(D) / (unsigned)npb;                       \
            unsigned ld = (unsigned)(D) - bb * (unsigned)npb;                  \
            unsigned idx = (unsigned)base[bb] + (unsigned)atomicAdd(&lcur[bb], 1); \
            if (idx < ebtot) ebuf[idx] = (ld << 17) | (unsigned)(S); }
        SCAT(d4.x, s4.x) SCAT(d4.y, s4.y) SCAT(d4.z, s4.z) SCAT(d4.w, s4.w)
    }
    for (int e = e0 + ng * 4 + tid; e < e1; e += 1024) {     // tail
        SCAT(dst[e], src[e])
    }
    #undef SCAT
}

// One WG per bucket b: edges in [b*cap, b*cap + bcur[b]); node histogram ->
// padded scan -> meta/dinv + csr fill (rows padded to %8, dummy src = N).
// csr region for bucket b = [b*ccap ...).
__global__ __launch_bounds__(1024) void k_bfill(const unsigned* __restrict__ ebuf,
        const int* __restrict__ bcur, int4* __restrict__ meta,
        float* __restrict__ dinv, int* __restrict__ csr, int N, int npb,
        int cap, int ccap) {
    __shared__ int h[512], p[512], c[512];
    int b = blockIdx.x, tid = threadIdx.x;
    int vlo = b * npb;
    int vcnt = min(npb, N - vlo);
    if (vcnt <= 0) return;                    // uniform across block
    int ed0 = b * cap;
    int ed1 = ed0 + min(bcur[b], cap);
    for (int i = tid; i < 512; i += 1024) h[i] = 0;
    __syncthreads();
    for (int e = ed0 + tid; e < ed1; e += 1024)
        atomicAdd(&h[ebuf[e] >> 17], 1);
    __syncthreads();
    int pc = 0;
    if (tid < 512) {
        pc = (tid < vcnt) ? ((h[tid] + 7) & ~7) : 0;   // padded count
        p[tid] = pc;
    }
    __syncthreads();
    for (int off = 1; off < 512; off <<= 1) { // Hillis-Steele inclusive scan
        int v = 0;
        if (tid < 512 && tid >= off) v = p[tid - off];
        __syncthreads();
        if (tid < 512) p[tid] += v;
        __syncthreads();
    }
    int bb = b * ccap;                        // bucket's csr base
    if (tid < vcnt) {
        int excl = p[tid] - pc;
        int v = vlo + tid;
        float di = rsqrtf((float)(h[tid] + 1));
        meta[v] = make_int4(bb + excl, pc >> 3, __float_as_int(di), 0);
        dinv[v] = di;
        c[tid] = excl;
    }
    __syncthreads();
    for (int e = ed0 + tid; e < ed1; e += 1024) {
        unsigned ed = ebuf[e];
        int off = atomicAdd(&c[ed >> 17], 1);
        csr[bb + off] = (int)(ed & 0x1FFFFu);
    }
    __syncthreads();
    if (tid < vcnt) {                         // zero-row padding entries
        int excl = p[tid] - pc;
        for (int q = excl + h[tid]; q < excl + pc; ++q) csr[bb + q] = N;
    }
}

// ---------------- MFMA GEMMs ----------------
// D col=lane&15 (feature in ntile), row=(lane>>4)*4+r (node in 16).
#define MFMA_EPILOGUE(OUT)                                                     \
    {                                                                          \
        int col = lane & 15;                                                   \
        float dv[4];                                                           \
        for (int r = 0; r < 4; ++r) {                                          \
            int vr = v0 + quad * 4 + r;                                        \
            dv[r] = dinv[vr < n ? vr : (n - 1)];                               \
        }                                                                      \
        for (int nt = 0; nt < 4; ++nt)                                         \
            for (int r = 0; r < 4; ++r) {                                      \
                int vr = v0 + quad * 4 + r;                                    \
                float val = acc[nt][r] * dv[r];                                \
                float oth = __shfl_xor(val, 1, 64);                            \
                if (!(lane & 1) && vr < n)                                     \
                    OUT[(size_t)vr * 32 + nt * 8 + (col >> 1)] =               \
                        bf16_bits(val) | (bf16_bits(oth) << 16);               \
            }                                                                  \
    }

// hs1 = dinv * (X @ W1). X staged via wave-private LDS (coalesced 1KB loads).
// Block 0 also zeroes pad-row N of hsb (ebuf aliased it until k_bfill ran).
__global__ __launch_bounds__(256) void k_mgemm1(const float* __restrict__ X,
        const uint4* __restrict__ W1s, const float* __restrict__ dinv,
        unsigned* __restrict__ hsb, int n) {
    __shared__ float Xs[4][16 * 132];         // 16 rows, +4 pad per row
    if (blockIdx.x == 0 && threadIdx.x < 32) hsb[(size_t)n * 32 + threadIdx.x] = 0;
    int lane = threadIdx.x & 63, wv = threadIdx.x >> 6;
    int v0 = (blockIdx.x * 4 + wv) * 16;
    if (v0 >= n) return;                      // wave-uniform
    const float4* X4 = (const float4*)X;
#pragma unroll
    for (int i = 0; i < 8; ++i) {             // stage 16 rows (8KB), coalesced
        int gi = i * 64 + lane;
        int r = gi >> 5, c4 = gi & 31;
        int vr = v0 + r; if (vr >= n) vr = n - 1;
        float4 t = X4[(size_t)vr * 32 + c4];
        *(float4*)&Xs[wv][r * 132 + c4 * 4] = t;
    }
    // wave-private LDS: no barrier needed
    int quad = lane >> 4;
    const float* xr = &Xs[wv][(lane & 15) * 132 + quad * 8];
    f32x4 acc[4] = {f32x4{0,0,0,0}, f32x4{0,0,0,0}, f32x4{0,0,0,0}, f32x4{0,0,0,0}};
#pragma unroll
    for (int kt = 0; kt < 4; ++kt) {
        float4 xa = *(const float4*)(xr + kt * 32);
        float4 xb = *(const float4*)(xr + kt * 32 + 4);
        FragU a;
        a.u.x = bf16_bits(xa.x) | (bf16_bits(xa.y) << 16);
        a.u.y = bf16_bits(xa.z) | (bf16_bits(xa.w) << 16);
        a.u.z = bf16_bits(xb.x) | (bf16_bits(xb.y) << 16);
        a.u.w = bf16_bits(xb.z) | (bf16_bits(xb.w) << 16);
#pragma unroll
        for (int nt = 0; nt < 4; ++nt) {
            FragU bfr; bfr.u = W1s[(kt * 4 + nt) * 64 + lane];
            acc[nt] = __builtin_amdgcn_mfma_f32_16x16x32_bf16(a.s, bfr.s, acc[nt], 0, 0, 0);
        }
    }
    MFMA_EPILOGUE(hsb)
}

// hs2 = dinv * (h1 @ W2), h1 bf16-packed [N,32 uints], out same format.
// Block 0 also zeroes pad-row N of hsbB.
__global__ __launch_bounds__(256) void k_mgemm2(const unsigned* __restrict__ h1b,
        const uint4* __restrict__ W2s, const float* __restrict__ dinv,
        unsigned* __restrict__ hsbB, int n) {
    if (blockIdx.x == 0 && threadIdx.x < 32) hsbB[(size_t)n * 32 + threadIdx.x] = 0;
    int lane = threadIdx.x & 63, wv = threadIdx.x >> 6;
    int v0 = (blockIdx.x * 4 + wv) * 16;
    if (v0 >= n) return;
    int quad = lane >> 4;
    int vm = v0 + (lane & 15); if (vm >= n) vm = n - 1;
    const uint4* h4 = (const uint4*)h1b;
    f32x4 acc[4] = {f32x4{0,0,0,0}, f32x4{0,0,0,0}, f32x4{0,0,0,0}, f32x4{0,0,0,0}};
#pragma unroll
    for (int kt = 0; kt < 2; ++kt) {
        FragU a; a.u = h4[(size_t)vm * 8 + kt * 4 + quad];
#pragma unroll
        for (int nt = 0; nt < 4; ++nt) {
            FragU bfr; bfr.u = W2s[(kt * 4 + nt) * 64 + lane];
            acc[nt] = __builtin_amdgcn_mfma_f32_16x16x32_bf16(a.s, bfr.s, acc[nt], 0, 0, 0);
        }
    }
    MFMA_EPILOGUE(hsbB)
}

// ---------------- conv gather (wave per node, padded, shfl broadcast) -------
#define GATHER_BODY                                                            \
    const uint4* hs4p = (const uint4*)hsb;                                     \
    int o = lane & 7, oct = lane >> 3;                                         \
    int4 mt = meta[v];                                                         \
    int rs = mt.x, nb = mt.y;                                                  \
    float dv = __int_as_float(mt.z);                                           \
    f32x2 A0 = {0.f,0.f}, A1 = {0.f,0.f}, A2 = {0.f,0.f}, A3 = {0.f,0.f};      \
    if (oct == 0) {                                                            \
        uint4 s = hs4p[(size_t)v * 8 + o];                                     \
        A0 = (f32x2){bflo(s.x), bfhi(s.x)};                                    \
        A1 = (f32x2){bflo(s.y), bfhi(s.y)};                                    \
        A2 = (f32x2){bflo(s.z), bfhi(s.z)};                                    \
        A3 = (f32x2){bflo(s.w), bfhi(s.w)};                                    \
    }                                                                          \
    for (int base = 0; base < nb; base += 8) {                                 \
        int idx = csr[rs + base * 8 + lane];  /* overread ok: csr has slack */ \
        int m = nb - base; if (m > 8) m = 8;  /* wave-uniform */               \
        uint4 wb[8];                                                           \
        _Pragma("unroll")                                                      \
        for (int i = 0; i < 8; ++i)                                            \
            if (i < m) {                                                       \
                int u = __shfl(idx, i * 8 + oct, 64);                          \
                wb[i] = hs4p[(size_t)u * 8 + o];                               \
            }                                                                  \
        _Pragma("unroll")                                                      \
        for (int i = 0; i < 8; ++i)                                            \
            if (i < m) {                                                       \
                A0 += (f32x2){bflo(wb[i].x), bfhi(wb[i].x)};                   \
                A1 += (f32x2){bflo(wb[i].y), bfhi(wb[i].y)};                   \
                A2 += (f32x2){bflo(wb[i].z), bfhi(wb[i].z)};                   \
                A3 += (f32x2){bflo(wb[i].w), bfhi(wb[i].w)};                   \
            }                                                                  \
    }                                                                          \
    A0.x += __shfl_xor(A0.x, 8, 64); A0.x += __shfl_xor(A0.x, 16, 64);         \
    A0.x += __shfl_xor(A0.x, 32, 64);                                          \
    A0.y += __shfl_xor(A0.y, 8, 64); A0.y += __shfl_xor(A0.y, 16, 64);         \
    A0.y += __shfl_xor(A0.y, 32, 64);                                          \
    A1.x += __shfl_xor(A1.x, 8, 64); A1.x += __shfl_xor(A1.x, 16, 64);         \
    A1.x += __shfl_xor(A1.x, 32, 64);                                          \
    A1.y += __shfl_xor(A1.y, 8, 64); A1.y += __shfl_xor(A1.y, 16, 64);         \
    A1.y += __shfl_xor(A1.y, 32, 64);                                          \
    A2.x += __shfl_xor(A2.x, 8, 64); A2.x += __shfl_xor(A2.x, 16, 64);         \
    A2.x += __shfl_xor(A2.x, 32, 64);                                          \
    A2.y += __shfl_xor(A2.y, 8, 64); A2.y += __shfl_xor(A2.y, 16, 64);         \
    A2.y += __shfl_xor(A2.y, 32, 64);                                          \
    A3.x += __shfl_xor(A3.x, 8, 64); A3.x += __shfl_xor(A3.x, 16, 64);         \
    A3.x += __shfl_xor(A3.x, 32, 64);                                          \
    A3.y += __shfl_xor(A3.y, 8, 64); A3.y += __shfl_xor(A3.y, 16, 64);         \
    A3.y += __shfl_xor(A3.y, 32, 64);                                          \
    float4 bb0 = ((const float4*)bias)[2 * o];                                 \
    float4 bb1 = ((const float4*)bias)[2 * o + 1];                             \
    float r0 = fmaxf(fmaf(dv, A0.x, bb0.x), 0.f);                              \
    float r1 = fmaxf(fmaf(dv, A0.y, bb0.y), 0.f);                              \
    float r2 = fmaxf(fmaf(dv, A1.x, bb0.z), 0.f);                              \
    float r3 = fmaxf(fmaf(dv, A1.y, bb0.w), 0.f);                              \
    float r4 = fmaxf(fmaf(dv, A2.x, bb1.x), 0.f);                              \
    float r5 = fmaxf(fmaf(dv, A2.y, bb1.y), 0.f);                              \
    float r6 = fmaxf(fmaf(dv, A3.x, bb1.z), 0.f);                              \
    float r7 = fmaxf(fmaf(dv, A3.y, bb1.w), 0.f);

// conv1: gather hs1, h1 = relu(dinv*acc + b1), store h1 bf16-packed.
__global__ void k_conv1(const unsigned* __restrict__ hsb, const int4* __restrict__ meta,
                        const int* __restrict__ csr, const float* __restrict__ bias,
                        unsigned* __restrict__ h1b, int n) {
    int v = (blockIdx.x * 256 + threadIdx.x) >> 6;
    int lane = threadIdx.x & 63;
    if (v >= n) return;
    GATHER_BODY
    if (oct == 0) {
        uint4 pk;
        pk.x = bf16_bits(r0) | (bf16_bits(r1) << 16);
        pk.y = bf16_bits(r2) | (bf16_bits(r3) << 16);
        pk.z = bf16_bits(r4) | (bf16_bits(r5) << 16);
        pk.w = bf16_bits(r6) | (bf16_bits(r7) << 16);
        ((uint4*)h1b)[(size_t)v * 8 + o] = pk;
    }
}

// conv2 + head: gather hs2, h2 = relu(dinv*acc + b2), z[v] = h2 @ Wl.
__global__ void k_conv_out(const unsigned* __restrict__ hsb, const int4* __restrict__ meta,
                           const int* __restrict__ csr, const float* __restrict__ bias,
                           const float* __restrict__ Wl, float2* __restrict__ z, int n) {
    int v = (blockIdx.x * 256 + threadIdx.x) >> 6;
    int lane = threadIdx.x & 63;
    if (v >= n) return;
    GATHER_BODY
    const float4* Wl4 = (const float4*)Wl;    // [64][2] -> 2 rows per float4
    float4 wA = Wl4[4 * o + 0];
    float4 wB = Wl4[4 * o + 1];
    float4 wC = Wl4[4 * o + 2];
    float4 wD = Wl4[4 * o + 3];
    float c0 = r0*wA.x + r1*wA.z + r2*wB.x + r3*wB.z + r4*wC.x + r5*wC.z + r6*wD.x + r7*wD.z;
    float c1 = r0*wA.y + r1*wA.w + r2*wB.y + r3*wB.w + r4*wC.y + r5*wC.w + r6*wD.y + r7*wD.w;
    c0 += __shfl_xor(c0, 1, 64); c1 += __shfl_xor(c1, 1, 64);
    c0 += __shfl_xor(c0, 2, 64); c1 += __shfl_xor(c1, 2, 64);
    c0 += __shfl_xor(c0, 4, 64); c1 += __shfl_xor(c1, 4, 64);
    if (lane == 0) z[v] = make_float2(c0, c1);
}

static __device__ __forceinline__ int lower_bound(const int* __restrict__ a, int n, int key) {
    int lo = 0, hi = n;
    while (lo < hi) {
        int mid = (lo + hi) >> 1;
        if (a[mid] < key) lo = mid + 1; else hi = mid;
    }
    return lo;
}

// One wave per graph: out[g] = mean(z[lo:hi]) + bl  (batch sorted).
__global__ void k_pool_z(const float2* __restrict__ z, const int* __restrict__ batch,
                         const float* __restrict__ bl, float* __restrict__ out, int N, int B) {
    int g = (blockIdx.x * 256 + threadIdx.x) >> 6;
    int lane = threadIdx.x & 63;
    if (g >= B) return;
    int lo = lower_bound(batch, N, g);
    int hi = lower_bound(batch, N, g + 1);
    float c0 = 0.f, c1 = 0.f;
    for (int v = lo + lane; v < hi; v += 64) {
        float2 t = z[v];
        c0 += t.x; c1 += t.y;
    }
    #pragma unroll
    for (int off = 32; off; off >>= 1) {
        c0 += __shfl_xor(c0, off, 64);
        c1 += __shfl_xor(c1, off, 64);
    }
    if (lane == 0) {
        float inv = 1.0f / fmaxf((float)(hi - lo), 1.0f);
        out[g * 2 + 0] = c0 * inv + bl[0];
        out[g * 2 + 1] = c1 * inv + bl[1];
    }
}

extern "C" void kernel_launch(void* const* d_in, const int* in_sizes, int n_in,
                              void* d_out, int out_size, void* d_ws, size_t ws_size,
                              hipStream_t stream) {
    const float* x  = (const float*)d_in[0];   // [N,128] f32
    const int* edge = (const int*)d_in[1];     // [2,E] i32
    const int* batch= (const int*)d_in[2];     // [N] i32 (sorted)
    const float* W1 = (const float*)d_in[3];   // [128,64]
    const float* b1 = (const float*)d_in[4];   // [64]
    const float* W2 = (const float*)d_in[5];   // [64,64]
    const float* b2 = (const float*)d_in[6];   // [64]
    const float* Wl = (const float*)d_in[7];   // [64,2]
    const float* bl = (const float*)d_in[8];   // [2]
    float* out = (float*)d_out;

    const int N = in_sizes[2];
    const int E = in_sizes[1] / 2;
    const int B = out_size / 2;
    const int* srcp = edge;
    const int* dstp = edge + E;
    const int npb = (N + NB - 1) / NB;         // nodes per bucket (391 @ N=100K, <=512)
    const int mean = (E + NB - 1) / NB;        // ~12500 edges/bucket
    const int cap  = ((mean + mean / 2 + 2048) + 1023) & ~1023;  // ~1.7x mean (+74 sigma)
    const int ccap = ((cap + 7 * npb + 128) + 127) & ~127;       // csr ints per bucket

    // workspace carve-up (256B aligned); ~66 MB
    char* w = (char*)d_ws;
    auto carve = [&](size_t bytes) { void* p = (void*)w; w += (bytes + 255) & ~(size_t)255; return p; };
    int4*     meta    = (int4*)carve((size_t)N * 16);
    float*    dinv    = (float*)carve((size_t)N * 4);
    int*      bcur    = (int*)carve((NB + 8) * 4);
    uint4*    W1s     = (uint4*)carve(16 * 64 * 16);
    uint4*    W2s     = (uint4*)carve(8 * 64 * 16);
    int*      csr     = (int*)carve(((size_t)NB * ccap + 256) * 4);  // fixed-cap buckets
    // ebuf aliases hsbA+h1b (cap*NB*4 ~ 21.5MB < 25.6MB): both are written
    // only after k_bfill consumed ebuf. Pad-rows N zeroed by mgemm1/mgemm2.
    unsigned* hsbA    = (unsigned*)carve(((size_t)N + 1) * 32 * 4);
    unsigned* h1b     = (unsigned*)carve(((size_t)N + 1) * 32 * 4);  // bf16x2 relu'd h1
    unsigned* hsbB    = (unsigned*)carve(((size_t)N + 1) * 32 * 4);  // bf16x2 hs layer2
    float2*   zbuf    = (float2*)carve((size_t)N * 8);               // per-node head output
    unsigned* ebuf    = hsbA;

    int chunk = ((E + SGRID - 1) / SGRID + 3) & ~3;  // edges per block, %4==0
    int wbl = (N + 3) / 4;                      // 4 waves (nodes) per 256-thread block
    int gbl = (N + 63) / 64;                    // 64 nodes per MFMA-gemm block

    hipMemsetAsync(bcur, 0, NB * 4, stream);
    k_scatter<<<SGRID + 1, 1024, 0, stream>>>(srcp, dstp, bcur, ebuf,
                                              W1, W2, W1s, W2s, N, E, npb, chunk, cap);
    k_bfill<<<NB, 1024, 0, stream>>>(ebuf, bcur, meta, dinv, csr, N, npb, cap, ccap);

    k_mgemm1<<<gbl, 256, 0, stream>>>(x, W1s, dinv, hsbA, N);
    k_conv1<<<wbl, 256, 0, stream>>>(hsbA, meta, csr, b1, h1b, N);
    k_mgemm2<<<gbl, 256, 0, stream>>>(h1b, W2s, dinv, hsbB, N);
    k_conv_out<<<wbl, 256, 0, stream>>>(hsbB, meta, csr, b2, Wl, zbuf, N);

    k_pool_z<<<(B * 64 + 255) / 256, 256, 0, stream>>>(zbuf, batch, bl, out, N, B);
}